// Round 11
// baseline (331.734 us; speedup 1.0000x reference)
//
#include <hip/hip_runtime.h>
#include <math.h>

#define N_NODES 50000
#define N_EDGES 800000
#define N_GRAPHS 16
#define NODE_F 128
#define HID 64
#define OUT_F 128
#define HEADS 3
#define NEG 0.2f
#define FEAT (HEADS*HID)  // 192

typedef float f32x4 __attribute__((ext_vector_type(4)));
typedef float f32x2 __attribute__((ext_vector_type(2)));
typedef short bf16x8 __attribute__((ext_vector_type(8)));

#if defined(__has_builtin)
#if __has_builtin(__builtin_amdgcn_cvt_pk_f32_fp8) && __has_builtin(__builtin_amdgcn_cvt_pk_fp8_f32)
#define USE_FP8 1
#endif
#endif
#ifndef USE_FP8
#define USE_FP8 0
#endif

#if USE_FP8
#define FB 1  // bytes per stored feat element
#else
#define FB 2
#endif
// feat layout: [node][32 pair-groups][8*FB bytes]; group p = dims (2p,2p+1) x 3 heads (6*FB used)
#define GRP (8 * FB)
#define ROW (32 * GRP)

__device__ __forceinline__ ushort f2bf(float x) {
  union { float f; unsigned u; } v; v.f = x;
  unsigned r = v.u + 0x7fff + ((v.u >> 16) & 1);  // round-to-nearest-even
  return (ushort)(r >> 16);
}
__device__ __forceinline__ float bf2f(ushort x) {
  union { unsigned u; float f; } v; v.u = ((unsigned)x) << 16;
  return v.f;
}

// store one feat element: head hh, dim dd
__device__ __forceinline__ void feat_store(unsigned char* base, int n, int hh, int dd, float v) {
  size_t off = (size_t)n * ROW + (dd >> 1) * GRP + ((hh * 2 + (dd & 1)) * FB);
#if USE_FP8
  base[off] = (unsigned char)(__builtin_amdgcn_cvt_pk_fp8_f32(v, 0.f, 0, false) & 0xff);
#else
  *(ushort*)(base + off) = f2bf(v);
#endif
}

// ---------------- K0: feat = h @ fc_w.T via MFMA bf16; el/er in epilogue ----------------
#define GB0 ((N_NODES + 63) / 64)  // 782
__global__ __launch_bounds__(256) void k0_mfma(
    const float* __restrict__ h, const float* __restrict__ fc_w,
    const float* __restrict__ attn_l, const float* __restrict__ attn_r,
    unsigned char* __restrict__ feat, float* __restrict__ el, float* __restrict__ er)
{
  __shared__ ushort A[64][136];   // bf16, 272 B row stride
  __shared__ ushort Bs[192][40];  // bf16 K-slice, 80 B row stride
  const int tid = threadIdx.x;
  const int n0 = blockIdx.x * 64;

  for (int i = tid; i < 64 * 32; i += 256) {
    int r = i >> 5, c4 = i & 31;
    if (n0 + r < N_NODES) {
      float4 v = *(const float4*)(h + (size_t)(n0 + r) * NODE_F + c4 * 4);
      unsigned lo = f2bf(v.x) | ((unsigned)f2bf(v.y) << 16);
      unsigned hi = f2bf(v.z) | ((unsigned)f2bf(v.w) << 16);
      *(uint2*)&A[r][c4 * 4] = make_uint2(lo, hi);
    }
  }

  const int lane = tid & 63, wv = tid >> 6;
  const int m = lane & 15, kq = lane >> 4;

  f32x4 acc[12];
#pragma unroll
  for (int t = 0; t < 12; t++) acc[t] = (f32x4){0.f, 0.f, 0.f, 0.f};

  for (int kk = 0; kk < 4; kk++) {
    __syncthreads();
    for (int i = tid; i < 192 * 8; i += 256) {
      int r = i >> 3, c4 = i & 7;
      float4 v = *(const float4*)(fc_w + (size_t)r * NODE_F + kk * 32 + c4 * 4);
      unsigned lo = f2bf(v.x) | ((unsigned)f2bf(v.y) << 16);
      unsigned hi = f2bf(v.z) | ((unsigned)f2bf(v.w) << 16);
      *(uint2*)&Bs[r][c4 * 4] = make_uint2(lo, hi);
    }
    __syncthreads();
    bf16x8 af = *(const bf16x8*)&A[wv * 16 + m][kk * 32 + kq * 8];
#pragma unroll
    for (int t = 0; t < 12; t++) {
      bf16x8 bf = *(const bf16x8*)&Bs[t * 16 + m][kq * 8];
      acc[t] = __builtin_amdgcn_mfma_f32_16x16x32_bf16(af, bf, acc[t], 0, 0, 0);
    }
  }

  const int rbase = n0 + wv * 16 + kq * 4;
#pragma unroll
  for (int t = 0; t < 12; t++) {
    const int hh = t >> 2;              // head
    const int dd = (t & 3) * 16 + m;    // dim within head
#pragma unroll
    for (int reg = 0; reg < 4; reg++) {
      int n = rbase + reg;
      if (n < N_NODES) feat_store(feat, n, hh, dd, acc[t][reg]);
    }
  }

#pragma unroll
  for (int hh = 0; hh < HEADS; hh++) {
    float elv[4] = {0.f, 0.f, 0.f, 0.f};
    float erv[4] = {0.f, 0.f, 0.f, 0.f};
#pragma unroll
    for (int tt = 0; tt < 4; tt++) {
      int t = hh * 4 + tt;
      float al = attn_l[hh * HID + tt * 16 + m];
      float ar = attn_r[hh * HID + tt * 16 + m];
#pragma unroll
      for (int reg = 0; reg < 4; reg++) {
        elv[reg] = fmaf(acc[t][reg], al, elv[reg]);
        erv[reg] = fmaf(acc[t][reg], ar, erv[reg]);
      }
    }
#pragma unroll
    for (int reg = 0; reg < 4; reg++) {
#pragma unroll
      for (int off = 1; off < 16; off <<= 1) {
        elv[reg] += __shfl_xor(elv[reg], off, 64);
        erv[reg] += __shfl_xor(erv[reg], off, 64);
      }
      int n = rbase + reg;
      if (m == 0 && n < N_NODES) {
        el[(size_t)n * 4 + hh] = elv[reg];
        er[(size_t)n * 4 + hh] = erv[reg];
      }
    }
  }
}

// ---------------- K1: histogram standalone (8 VGPR, no LDS -> max occupancy) ----------------
__global__ void k1_hist(const int* __restrict__ dst, int* __restrict__ deg,
                        int* __restrict__ rank) {
  int e = blockIdx.x * 256 + threadIdx.x;  // grid exact E/256
  rank[e] = atomicAdd(&deg[dst[e]], 1);
}

// ---------------- K2: scan (block sums, then apply w/ inline block-offset) ----------------
#define SCAN_T 1024
#define SCAN_NB 49  // ceil(50000/1024)

__global__ __launch_bounds__(SCAN_T) void k2a_blocksum(
    const int* __restrict__ deg, int* __restrict__ bsum)
{
  const int tid = threadIdx.x;
  int idx = blockIdx.x * SCAN_T + tid;
  int v = (idx < N_NODES) ? deg[idx] : 0;
#pragma unroll
  for (int off = 32; off; off >>= 1) v += __shfl_xor(v, off, 64);
  __shared__ int ws_[16];
  if ((tid & 63) == 0) ws_[tid >> 6] = v;
  __syncthreads();
  if (tid == 0) {
    int s = 0;
    for (int i = 0; i < 16; i++) s += ws_[i];
    bsum[blockIdx.x] = s;
  }
}

__global__ __launch_bounds__(SCAN_T) void k2c_apply(
    const int* __restrict__ deg, const int* __restrict__ bsum,
    int* __restrict__ offs)
{
  __shared__ int wsum[16], woff[16], bo;
  const int tid = threadIdx.x;
  const int lane = tid & 63, wv = tid >> 6;
  const int idx = blockIdx.x * SCAN_T + tid;
  if (tid < 64) {
    int v = (tid < blockIdx.x) ? bsum[tid] : 0;  // blockIdx <= 48 < 64
#pragma unroll
    for (int off = 32; off; off >>= 1) v += __shfl_xor(v, off, 64);
    if (tid == 0) bo = v;
  }
  int v = (idx < N_NODES) ? deg[idx] : 0;
  int s = v;
#pragma unroll
  for (int off = 1; off < 64; off <<= 1) {
    int t = __shfl_up(s, off, 64);
    if (lane >= off) s += t;
  }
  if (lane == 63) wsum[wv] = s;
  __syncthreads();
  if (tid < 16) {
    int w = wsum[tid];
    int sc = w;
#pragma unroll
    for (int off = 1; off < 16; off <<= 1) {
      int t = __shfl_up(sc, off, 64);
      if (tid >= off) sc += t;
    }
    woff[tid] = sc - w;
  }
  __syncthreads();
  int excl = s - v + woff[wv] + bo;
  if (idx < N_NODES) offs[idx] = excl;
  if (blockIdx.x == 0 && tid == 0) offs[N_NODES] = N_EDGES;
}

// ---------------- K3: edge weights + NO-ATOMIC scatter {w0,w1,w2,byteoff} into CSR ----------------
__global__ __launch_bounds__(256) void k3_edge(
    const int* __restrict__ src, const int* __restrict__ dst,
    const float* __restrict__ el4, const float* __restrict__ er4,
    const int* __restrict__ offs, const int* __restrict__ rank,
    float4* __restrict__ csr_w)
{
  int e = blockIdx.x * 256 + threadIdx.x;  // grid exact E/256
  int s = src[e], d = dst[e];
  int pos = offs[d] + rank[e];
  float4 elv = ((const float4*)el4)[s];
  float4 erv = ((const float4*)er4)[d];
  float e0 = elv.x + erv.x; e0 = e0 > 0.f ? e0 : NEG * e0;
  float e1 = elv.y + erv.y; e1 = e1 > 0.f ? e1 : NEG * e1;
  float e2 = elv.z + erv.z; e2 = e2 > 0.f ? e2 : NEG * e2;
  float4 r;
  r.x = __expf(e0); r.y = __expf(e1); r.z = __expf(e2);
  r.w = __int_as_float(s * ROW);  // byte offset of feat row
  csr_w[pos] = r;
}

// ---------------- K4: wave per node, all heads, single sweep, ONE 8B gather/edge ----------------
__global__ __launch_bounds__(256) void k4_agg(
    const int* __restrict__ offs, const float4* __restrict__ csr_w,
    const unsigned char* __restrict__ feat, const float* __restrict__ bias,
    float* __restrict__ h_d)
{
  __shared__ float4 rec[4][64];  // per-wave staging, 4 KB/block
  const int wv = threadIdx.x >> 6, lane = threadIdx.x & 63;
  const int n = blockIdx.x * 4 + wv;  // grid exact: N/4
  const int lo = offs[n], hi = offs[n + 1];
  const int half = lane >> 5;
  const int d = lane & 31;
  const char* fb = (const char*)feat;

  float a0x = 0.f, a0y = 0.f, a1x = 0.f, a1y = 0.f, a2x = 0.f, a2y = 0.f;
  float s0 = 0.f, s1 = 0.f, s2 = 0.f;

  for (int base = lo; base < hi; base += 64) {
    const int cnt = min(64, hi - base);
    if (lane < cnt) {
      float4 c = csr_w[base + lane];
      rec[wv][lane] = c;
      s0 += c.x; s1 += c.y; s2 += c.z;  // each edge counted once (by its staging lane)
    }
#define K4_BODY(J) do { \
      float4 c = rec[wv][J]; \
      const char* rp = fb + __float_as_int(c.w) + GRP * d; \
      f32x2 f0, f1, f2; \
      if (USE_FP8) { \
        uint2 q = *(const uint2*)rp; \
        f0 = __builtin_amdgcn_cvt_pk_f32_fp8(q.x & 0xffff, false); \
        f1 = __builtin_amdgcn_cvt_pk_f32_fp8(q.x >> 16, false); \
        f2 = __builtin_amdgcn_cvt_pk_f32_fp8(q.y & 0xffff, false); \
      } else { \
        uint4 q = *(const uint4*)rp; \
        f0.x = bf2f((ushort)(q.x & 0xffff)); f0.y = bf2f((ushort)(q.x >> 16)); \
        f1.x = bf2f((ushort)(q.y & 0xffff)); f1.y = bf2f((ushort)(q.y >> 16)); \
        f2.x = bf2f((ushort)(q.z & 0xffff)); f2.y = bf2f((ushort)(q.z >> 16)); \
      } \
      a0x = fmaf(c.x, f0.x, a0x); a0y = fmaf(c.x, f0.y, a0y); \
      a1x = fmaf(c.y, f1.x, a1x); a1y = fmaf(c.y, f1.y, a1y); \
      a2x = fmaf(c.z, f2.x, a2x); a2y = fmaf(c.z, f2.y, a2y); \
    } while (0)
    int j = half;
    for (; j + 2 < cnt; j += 4) { K4_BODY(j); K4_BODY(j + 2); }
    if (j < cnt) K4_BODY(j);
#undef K4_BODY
  }
  // combine the two half-wave edge partitions (same dims, disjoint edges)
  a0x += __shfl_xor(a0x, 32, 64); a0y += __shfl_xor(a0y, 32, 64);
  a1x += __shfl_xor(a1x, 32, 64); a1y += __shfl_xor(a1y, 32, 64);
  a2x += __shfl_xor(a2x, 32, 64); a2y += __shfl_xor(a2y, 32, 64);
#pragma unroll
  for (int off = 32; off; off >>= 1) {
    s0 += __shfl_xor(s0, off, 64);
    s1 += __shfl_xor(s1, off, 64);
    s2 += __shfl_xor(s2, off, 64);
  }
  const float i0 = s0 > 0.f ? 1.f / s0 : 0.f;
  const float i1 = s1 > 0.f ? 1.f / s1 : 0.f;
  const float i2 = s2 > 0.f ? 1.f / s2 : 0.f;
  if (half == 0) {
    float2 b0 = *(const float2*)(bias + 2 * d);
    float2 b1 = *(const float2*)(bias + HID + 2 * d);
    float2 b2 = *(const float2*)(bias + 2 * HID + 2 * d);
    float2 o;
    o.x = (fmaf(a0x, i0, b0.x) + fmaf(a1x, i1, b1.x) + fmaf(a2x, i2, b2.x)) * (1.f / 3.f);
    o.y = (fmaf(a0y, i0, b0.y) + fmaf(a1y, i1, b1.y) + fmaf(a2y, i2, b2.y)) * (1.f / 3.f);
    *(float2*)(h_d + (size_t)n * HID + 2 * d) = o;
  }
}

// ---------------- K5a: atomic-free block partials (sorted graph_id, span<=2 fast path) ----------------
#define K5_NPB 128
#define K5_NB ((N_NODES + K5_NPB - 1) / K5_NPB)  // 391
__global__ __launch_bounds__(256) void k5a_partial(
    const int* __restrict__ graph_id, const float* __restrict__ h_d,
    float* __restrict__ pooled_res, int* __restrict__ gcnt_res,  // rare-path residue
    float* __restrict__ part, int* __restrict__ pg, int* __restrict__ pc)
{
  const int wv = threadIdx.x >> 6, lane = threadIdx.x & 63;
  const int b = blockIdx.x;
  const int n0 = b * K5_NPB;
  const int n1 = min(n0 + K5_NPB, N_NODES);
  const int g_lo = graph_id[n0], g_hi = graph_id[n1 - 1];

  if (g_hi > g_lo + 1) {
    // rare path (a graph smaller than the block span): per-wave atomic flush
    float acc = 0.f; int cur_g = -1; int cnt = 0;
    for (int i = n0 + wv; i < n1; i += 4) {
      int g = graph_id[i];
      if (g != cur_g) {
        if (cur_g >= 0) {
          atomicAdd(&pooled_res[cur_g * HID + lane], acc);
          if (lane == 0) atomicAdd(&gcnt_res[cur_g], cnt);
        }
        acc = 0.f; cnt = 0; cur_g = g;
      }
      acc += h_d[(size_t)i * HID + lane];
      cnt++;
    }
    if (cur_g >= 0) {
      atomicAdd(&pooled_res[cur_g * HID + lane], acc);
      if (lane == 0) atomicAdd(&gcnt_res[cur_g], cnt);
    }
    if (threadIdx.x < 2) pg[b * 2 + threadIdx.x] = -1;
    return;
  }

  // common path: branchless two-bucket accumulation, no atomics, no fences
  float acc_lo = 0.f, acc_hi = 0.f;
  int c_lo = 0, c_hi = 0;
  for (int i = n0 + wv; i < n1; i += 4) {
    int g = graph_id[i];
    float v = h_d[(size_t)i * HID + lane];
    bool hi = (g != g_lo);
    acc_hi += hi ? v : 0.f;
    acc_lo += hi ? 0.f : v;
    c_hi += hi ? 1 : 0;
    c_lo += hi ? 0 : 1;
  }
  __shared__ float ls[2][4][64];
  __shared__ int lc[2][4];
  ls[0][wv][lane] = acc_lo;
  ls[1][wv][lane] = acc_hi;
  if (lane == 0) { lc[0][wv] = c_lo; lc[1][wv] = c_hi; }
  __syncthreads();
  if (wv < 2) {
    float s = ls[wv][0][lane] + ls[wv][1][lane] + ls[wv][2][lane] + ls[wv][3][lane];
    part[((size_t)b * 2 + wv) * HID + lane] = s;
    if (lane == 0) {
      int cnt = lc[wv][0] + lc[wv][1] + lc[wv][2] + lc[wv][3];
      int gg = (wv == 0) ? g_lo : g_hi;
      if (wv == 1 && (g_hi == g_lo || cnt == 0)) gg = -1;
      pg[b * 2 + wv] = gg;
      pc[b * 2 + wv] = cnt;
    }
  }
}

// ---------------- K6: single-block final reduce + MLP head ----------------
__global__ __launch_bounds__(256) void k6_final(
    const float* __restrict__ part, const int* __restrict__ pg, const int* __restrict__ pc,
    const float* __restrict__ pooled_res, const int* __restrict__ gcnt_res,
    const float* __restrict__ z,
    const float* __restrict__ lin1_w, const float* __restrict__ lin1_b,
    const float* __restrict__ lin2_w, const float* __restrict__ lin2_b,
    float* __restrict__ out)
{
  __shared__ float pools[4][N_GRAPHS][HID];  // per-wave private copies (16 KB)
  __shared__ int cnts[4][N_GRAPHS];
  __shared__ float cat[N_GRAPHS][2 * HID];
  __shared__ float inv_cnt[N_GRAPHS];
  const int tid = threadIdx.x, wv = tid >> 6, lane = tid & 63;

#pragma unroll
  for (int g = 0; g < N_GRAPHS; g++) pools[wv][g][lane] = 0.f;
  if (lane < N_GRAPHS) cnts[wv][lane] = 0;
  // no sync needed: each wave touches only its own copy below

  for (int s = wv; s < K5_NB * 2; s += 4) {
    int g = pg[s];
    if (g >= 0) {
      pools[wv][g][lane] += part[(size_t)s * HID + lane];
      if (lane == 0) cnts[wv][g] += pc[s];
    }
  }
  __syncthreads();

  if (tid < N_GRAPHS) {
    int g = tid;
    int c = cnts[0][g] + cnts[1][g] + cnts[2][g] + cnts[3][g] + gcnt_res[g];
    inv_cnt[g] = 1.f / (float)(c > 0 ? c : 1);
  }
  __syncthreads();
  for (int i = tid; i < N_GRAPHS * HID; i += 256) {
    int g = i >> 6, l = i & 63;
    float s = pools[0][g][l] + pools[1][g][l] + pools[2][g][l] + pools[3][g][l]
            + pooled_res[g * HID + l];
    cat[g][l] = s * inv_cnt[g];
  }
  __syncthreads();
  for (int i = tid; i < N_GRAPHS * HID; i += 256) {
    int g = i >> 6, j = i & 63;
    float s = lin1_b[j];
    const float* zr = z + g * OUT_F;
    const float* wr = lin1_w + j * OUT_F;
    for (int k = 0; k < OUT_F; k += 4) {
      float4 zv = *(const float4*)(zr + k);
      float4 wv4 = *(const float4*)(wr + k);
      s = fmaf(zv.x, wv4.x, fmaf(zv.y, wv4.y, fmaf(zv.z, wv4.z, fmaf(zv.w, wv4.w, s))));
    }
    cat[g][HID + j] = s;
  }
  __syncthreads();
  if (tid < N_GRAPHS) {
    float s = lin2_b[0];
    for (int i = 0; i < 2 * HID; i++) s += cat[tid][i] * lin2_w[i];
    out[tid] = 1.f / (1.f + __expf(-s));
  }
}

extern "C" void kernel_launch(void* const* d_in, const int* in_sizes, int n_in,
                              void* d_out, int out_size, void* d_ws, size_t ws_size,
                              hipStream_t stream) {
  (void)in_sizes; (void)n_in; (void)out_size; (void)ws_size;
  const float* h      = (const float*)d_in[0];
  const float* z      = (const float*)d_in[1];
  const int*   src    = (const int*)d_in[2];
  const int*   dst    = (const int*)d_in[3];
  const int*   gid    = (const int*)d_in[4];
  const float* fc_w   = (const float*)d_in[5];
  const float* attn_l = (const float*)d_in[6];
  const float* attn_r = (const float*)d_in[7];
  const float* bias   = (const float*)d_in[8];
  const float* lin1_w = (const float*)d_in[9];
  const float* lin1_b = (const float*)d_in[10];
  const float* lin2_w = (const float*)d_in[11];
  const float* lin2_b = (const float*)d_in[12];
  float* out = (float*)d_out;

  // workspace layout (~41 MB)
  float4* csr_w     = (float4*)d_ws;                            // E float4 (12.8 MB)
  unsigned char* feat = (unsigned char*)(csr_w + N_EDGES);      // N*ROW bytes
  float* h_d        = (float*)(feat + (size_t)N_NODES * ROW);   // N*64 fp32
  float* el         = h_d + (size_t)N_NODES * HID;              // N*4
  float* er         = el + (size_t)N_NODES * 4;                 // N*4
  float* part       = er + (size_t)N_NODES * 4;                 // K5_NB*2*64 (~200 KB)
  int* pg           = (int*)(part + (size_t)K5_NB * 2 * HID);   // K5_NB*2
  int* pc           = pg + K5_NB * 2;                           // K5_NB*2
  // --- zeroed region: pooled_res, gcnt_res, deg (contiguous, one memset) ---
  float* pooled_res = (float*)(pc + K5_NB * 2);                 // 16*64
  int* gcnt_res     = (int*)(pooled_res + N_GRAPHS * HID);      // 16
  int* deg          = gcnt_res + N_GRAPHS;                      // N+1
  // --- end zeroed region ---
  int* offs         = deg + (N_NODES + 1);                      // N+1
  int* rank         = offs + (N_NODES + 1);                     // E
  int* bsum         = rank + N_EDGES;                           // 49

  size_t zero_bytes = N_GRAPHS * HID * sizeof(float) + N_GRAPHS * sizeof(int)
                    + (N_NODES + 1) * sizeof(int);
  hipMemsetAsync(pooled_res, 0, zero_bytes, stream);

  k0_mfma<<<GB0, 256, 0, stream>>>(h, fc_w, attn_l, attn_r, feat, el, er);
  k1_hist<<<N_EDGES / 256, 256, 0, stream>>>(dst, deg, rank);
  k2a_blocksum<<<SCAN_NB, SCAN_T, 0, stream>>>(deg, bsum);
  k2c_apply<<<SCAN_NB, SCAN_T, 0, stream>>>(deg, bsum, offs);
  k3_edge<<<N_EDGES / 256, 256, 0, stream>>>(src, dst, el, er, offs, rank, csr_w);
  k4_agg<<<N_NODES / 4, 256, 0, stream>>>(offs, csr_w, feat, bias, h_d);
  k5a_partial<<<K5_NB, 256, 0, stream>>>(gid, h_d, pooled_res, gcnt_res, part, pg, pc);
  k6_final<<<1, 256, 0, stream>>>(part, pg, pc, pooled_res, gcnt_res,
                                  z, lin1_w, lin1_b, lin2_w, lin2_b, out);
}

// Round 12
// 248.757 us; speedup vs baseline: 1.3336x; 1.3336x over previous
//
#include <hip/hip_runtime.h>
#include <math.h>

#define N_NODES 50000
#define N_EDGES 800000
#define N_GRAPHS 16
#define NODE_F 128
#define HID 64
#define OUT_F 128
#define HEADS 3
#define NEG 0.2f
#define FEAT (HEADS*HID)  // 192

typedef float f32x4 __attribute__((ext_vector_type(4)));
typedef float f32x2 __attribute__((ext_vector_type(2)));
typedef short bf16x8 __attribute__((ext_vector_type(8)));

#if defined(__has_builtin)
#if __has_builtin(__builtin_amdgcn_cvt_pk_f32_fp8) && __has_builtin(__builtin_amdgcn_cvt_pk_fp8_f32)
#define USE_FP8 1
#endif
#endif
#ifndef USE_FP8
#define USE_FP8 0
#endif

#if USE_FP8
#define FB 1  // bytes per stored feat element
#else
#define FB 2
#endif
// feat layout: [node][32 pair-groups][8*FB bytes]; group p = dims (2p,2p+1) x 3 heads (6*FB used)
#define GRP (8 * FB)
#define ROW (32 * GRP)

__device__ __forceinline__ ushort f2bf(float x) {
  union { float f; unsigned u; } v; v.f = x;
  unsigned r = v.u + 0x7fff + ((v.u >> 16) & 1);  // round-to-nearest-even
  return (ushort)(r >> 16);
}
__device__ __forceinline__ float bf2f(ushort x) {
  union { unsigned u; float f; } v; v.u = ((unsigned)x) << 16;
  return v.f;
}

// store one feat element: head hh, dim dd
__device__ __forceinline__ void feat_store(unsigned char* base, int n, int hh, int dd, float v) {
  size_t off = (size_t)n * ROW + (dd >> 1) * GRP + ((hh * 2 + (dd & 1)) * FB);
#if USE_FP8
  base[off] = (unsigned char)(__builtin_amdgcn_cvt_pk_fp8_f32(v, 0.f, 0, false) & 0xff);
#else
  *(ushort*)(base + off) = f2bf(v);
#endif
}

// ---------------- K0: feat = h @ fc_w.T via MFMA bf16; el/er in epilogue ----------------
#define GB0 ((N_NODES + 63) / 64)  // 782
__global__ __launch_bounds__(256) void k0_mfma(
    const float* __restrict__ h, const float* __restrict__ fc_w,
    const float* __restrict__ attn_l, const float* __restrict__ attn_r,
    unsigned char* __restrict__ feat, float* __restrict__ el, float* __restrict__ er)
{
  __shared__ ushort A[64][136];   // bf16, 272 B row stride
  __shared__ ushort Bs[192][40];  // bf16 K-slice, 80 B row stride
  const int tid = threadIdx.x;
  const int n0 = blockIdx.x * 64;

  for (int i = tid; i < 64 * 32; i += 256) {
    int r = i >> 5, c4 = i & 31;
    if (n0 + r < N_NODES) {
      float4 v = *(const float4*)(h + (size_t)(n0 + r) * NODE_F + c4 * 4);
      unsigned lo = f2bf(v.x) | ((unsigned)f2bf(v.y) << 16);
      unsigned hi = f2bf(v.z) | ((unsigned)f2bf(v.w) << 16);
      *(uint2*)&A[r][c4 * 4] = make_uint2(lo, hi);
    }
  }

  const int lane = tid & 63, wv = tid >> 6;
  const int m = lane & 15, kq = lane >> 4;

  f32x4 acc[12];
#pragma unroll
  for (int t = 0; t < 12; t++) acc[t] = (f32x4){0.f, 0.f, 0.f, 0.f};

  for (int kk = 0; kk < 4; kk++) {
    __syncthreads();
    for (int i = tid; i < 192 * 8; i += 256) {
      int r = i >> 3, c4 = i & 7;
      float4 v = *(const float4*)(fc_w + (size_t)r * NODE_F + kk * 32 + c4 * 4);
      unsigned lo = f2bf(v.x) | ((unsigned)f2bf(v.y) << 16);
      unsigned hi = f2bf(v.z) | ((unsigned)f2bf(v.w) << 16);
      *(uint2*)&Bs[r][c4 * 4] = make_uint2(lo, hi);
    }
    __syncthreads();
    bf16x8 af = *(const bf16x8*)&A[wv * 16 + m][kk * 32 + kq * 8];
#pragma unroll
    for (int t = 0; t < 12; t++) {
      bf16x8 bf = *(const bf16x8*)&Bs[t * 16 + m][kq * 8];
      acc[t] = __builtin_amdgcn_mfma_f32_16x16x32_bf16(af, bf, acc[t], 0, 0, 0);
    }
  }

  const int rbase = n0 + wv * 16 + kq * 4;
#pragma unroll
  for (int t = 0; t < 12; t++) {
    const int hh = t >> 2;              // head
    const int dd = (t & 3) * 16 + m;    // dim within head
#pragma unroll
    for (int reg = 0; reg < 4; reg++) {
      int n = rbase + reg;
      if (n < N_NODES) feat_store(feat, n, hh, dd, acc[t][reg]);
    }
  }

#pragma unroll
  for (int hh = 0; hh < HEADS; hh++) {
    float elv[4] = {0.f, 0.f, 0.f, 0.f};
    float erv[4] = {0.f, 0.f, 0.f, 0.f};
#pragma unroll
    for (int tt = 0; tt < 4; tt++) {
      int t = hh * 4 + tt;
      float al = attn_l[hh * HID + tt * 16 + m];
      float ar = attn_r[hh * HID + tt * 16 + m];
#pragma unroll
      for (int reg = 0; reg < 4; reg++) {
        elv[reg] = fmaf(acc[t][reg], al, elv[reg]);
        erv[reg] = fmaf(acc[t][reg], ar, erv[reg]);
      }
    }
#pragma unroll
    for (int reg = 0; reg < 4; reg++) {
#pragma unroll
      for (int off = 1; off < 16; off <<= 1) {
        elv[reg] += __shfl_xor(elv[reg], off, 64);
        erv[reg] += __shfl_xor(erv[reg], off, 64);
      }
      int n = rbase + reg;
      if (m == 0 && n < N_NODES) {
        el[(size_t)n * 4 + hh] = elv[reg];
        er[(size_t)n * 4 + hh] = erv[reg];
      }
    }
  }
}

// ---------------- K1: histogram standalone (8 VGPR, no LDS -> max occupancy) ----------------
__global__ void k1_hist(const int* __restrict__ dst, int* __restrict__ deg,
                        int* __restrict__ rank) {
  int e = blockIdx.x * 256 + threadIdx.x;  // grid exact E/256
  rank[e] = atomicAdd(&deg[dst[e]], 1);
}

// ---------------- K2: scan (block sums, then apply w/ inline block-offset) ----------------
#define SCAN_T 1024
#define SCAN_NB 49  // ceil(50000/1024)

__global__ __launch_bounds__(SCAN_T) void k2a_blocksum(
    const int* __restrict__ deg, int* __restrict__ bsum)
{
  const int tid = threadIdx.x;
  int idx = blockIdx.x * SCAN_T + tid;
  int v = (idx < N_NODES) ? deg[idx] : 0;
#pragma unroll
  for (int off = 32; off; off >>= 1) v += __shfl_xor(v, off, 64);
  __shared__ int ws_[16];
  if ((tid & 63) == 0) ws_[tid >> 6] = v;
  __syncthreads();
  if (tid == 0) {
    int s = 0;
    for (int i = 0; i < 16; i++) s += ws_[i];
    bsum[blockIdx.x] = s;
  }
}

__global__ __launch_bounds__(SCAN_T) void k2c_apply(
    const int* __restrict__ deg, const int* __restrict__ bsum,
    int* __restrict__ offs)
{
  __shared__ int wsum[16], woff[16], bo;
  const int tid = threadIdx.x;
  const int lane = tid & 63, wv = tid >> 6;
  const int idx = blockIdx.x * SCAN_T + tid;
  if (tid < 64) {
    int v = (tid < blockIdx.x) ? bsum[tid] : 0;  // blockIdx <= 48 < 64
#pragma unroll
    for (int off = 32; off; off >>= 1) v += __shfl_xor(v, off, 64);
    if (tid == 0) bo = v;
  }
  int v = (idx < N_NODES) ? deg[idx] : 0;
  int s = v;
#pragma unroll
  for (int off = 1; off < 64; off <<= 1) {
    int t = __shfl_up(s, off, 64);
    if (lane >= off) s += t;
  }
  if (lane == 63) wsum[wv] = s;
  __syncthreads();
  if (tid < 16) {
    int w = wsum[tid];
    int sc = w;
#pragma unroll
    for (int off = 1; off < 16; off <<= 1) {
      int t = __shfl_up(sc, off, 64);
      if (tid >= off) sc += t;
    }
    woff[tid] = sc - w;
  }
  __syncthreads();
  int excl = s - v + woff[wv] + bo;
  if (idx < N_NODES) offs[idx] = excl;
  if (blockIdx.x == 0 && tid == 0) offs[N_NODES] = N_EDGES;
}

// ---------------- K3: edge weights + NO-ATOMIC scatter {w0,w1,w2,byteoff} into CSR ----------------
__global__ __launch_bounds__(256) void k3_edge(
    const int* __restrict__ src, const int* __restrict__ dst,
    const float* __restrict__ el4, const float* __restrict__ er4,
    const int* __restrict__ offs, const int* __restrict__ rank,
    float4* __restrict__ csr_w)
{
  int e = blockIdx.x * 256 + threadIdx.x;  // grid exact E/256
  int s = src[e], d = dst[e];
  int pos = offs[d] + rank[e];
  float4 elv = ((const float4*)el4)[s];
  float4 erv = ((const float4*)er4)[d];
  float e0 = elv.x + erv.x; e0 = e0 > 0.f ? e0 : NEG * e0;
  float e1 = elv.y + erv.y; e1 = e1 > 0.f ? e1 : NEG * e1;
  float e2 = elv.z + erv.z; e2 = e2 > 0.f ? e2 : NEG * e2;
  float4 r;
  r.x = __expf(e0); r.y = __expf(e1); r.z = __expf(e2);
  r.w = __int_as_float(s * ROW);  // byte offset of feat row
  csr_w[pos] = r;
}

// ---------------- K4: wave per node, all heads, single sweep, ONE 8B gather/edge ----------------
__global__ __launch_bounds__(256) void k4_agg(
    const int* __restrict__ offs, const float4* __restrict__ csr_w,
    const unsigned char* __restrict__ feat, const float* __restrict__ bias,
    float* __restrict__ h_d)
{
  __shared__ float4 rec[4][64];  // per-wave staging, 4 KB/block
  const int wv = threadIdx.x >> 6, lane = threadIdx.x & 63;
  const int n = blockIdx.x * 4 + wv;  // grid exact: N/4
  const int lo = offs[n], hi = offs[n + 1];
  const int half = lane >> 5;
  const int d = lane & 31;
  const char* fb = (const char*)feat;

  float a0x = 0.f, a0y = 0.f, a1x = 0.f, a1y = 0.f, a2x = 0.f, a2y = 0.f;
  float s0 = 0.f, s1 = 0.f, s2 = 0.f;

  for (int base = lo; base < hi; base += 64) {
    const int cnt = min(64, hi - base);
    if (lane < cnt) {
      float4 c = csr_w[base + lane];
      rec[wv][lane] = c;
      s0 += c.x; s1 += c.y; s2 += c.z;  // each edge counted once (by its staging lane)
    }
#define K4_BODY(J) do { \
      float4 c = rec[wv][J]; \
      const char* rp = fb + __float_as_int(c.w) + GRP * d; \
      f32x2 f0, f1, f2; \
      if (USE_FP8) { \
        uint2 q = *(const uint2*)rp; \
        f0 = __builtin_amdgcn_cvt_pk_f32_fp8(q.x & 0xffff, false); \
        f1 = __builtin_amdgcn_cvt_pk_f32_fp8(q.x >> 16, false); \
        f2 = __builtin_amdgcn_cvt_pk_f32_fp8(q.y & 0xffff, false); \
      } else { \
        uint4 q = *(const uint4*)rp; \
        f0.x = bf2f((ushort)(q.x & 0xffff)); f0.y = bf2f((ushort)(q.x >> 16)); \
        f1.x = bf2f((ushort)(q.y & 0xffff)); f1.y = bf2f((ushort)(q.y >> 16)); \
        f2.x = bf2f((ushort)(q.z & 0xffff)); f2.y = bf2f((ushort)(q.z >> 16)); \
      } \
      a0x = fmaf(c.x, f0.x, a0x); a0y = fmaf(c.x, f0.y, a0y); \
      a1x = fmaf(c.y, f1.x, a1x); a1y = fmaf(c.y, f1.y, a1y); \
      a2x = fmaf(c.z, f2.x, a2x); a2y = fmaf(c.z, f2.y, a2y); \
    } while (0)
    int j = half;
    for (; j + 2 < cnt; j += 4) { K4_BODY(j); K4_BODY(j + 2); }
    if (j < cnt) K4_BODY(j);
#undef K4_BODY
  }
  // combine the two half-wave edge partitions (same dims, disjoint edges)
  a0x += __shfl_xor(a0x, 32, 64); a0y += __shfl_xor(a0y, 32, 64);
  a1x += __shfl_xor(a1x, 32, 64); a1y += __shfl_xor(a1y, 32, 64);
  a2x += __shfl_xor(a2x, 32, 64); a2y += __shfl_xor(a2y, 32, 64);
#pragma unroll
  for (int off = 32; off; off >>= 1) {
    s0 += __shfl_xor(s0, off, 64);
    s1 += __shfl_xor(s1, off, 64);
    s2 += __shfl_xor(s2, off, 64);
  }
  const float i0 = s0 > 0.f ? 1.f / s0 : 0.f;
  const float i1 = s1 > 0.f ? 1.f / s1 : 0.f;
  const float i2 = s2 > 0.f ? 1.f / s2 : 0.f;
  if (half == 0) {
    float2 b0 = *(const float2*)(bias + 2 * d);
    float2 b1 = *(const float2*)(bias + HID + 2 * d);
    float2 b2 = *(const float2*)(bias + 2 * HID + 2 * d);
    float2 o;
    o.x = (fmaf(a0x, i0, b0.x) + fmaf(a1x, i1, b1.x) + fmaf(a2x, i2, b2.x)) * (1.f / 3.f);
    o.y = (fmaf(a0y, i0, b0.y) + fmaf(a1y, i1, b1.y) + fmaf(a2y, i2, b2.y)) * (1.f / 3.f);
    *(float2*)(h_d + (size_t)n * HID + 2 * d) = o;
  }
}

// ---------------- K5a: atomic-free block partials (sorted graph_id, span<=2 fast path) ----------------
#define K5_NPB 128
#define K5_NB ((N_NODES + K5_NPB - 1) / K5_NPB)  // 391
#define NSEG (K5_NB * 2)                         // 782
__global__ __launch_bounds__(256) void k5a_partial(
    const int* __restrict__ graph_id, const float* __restrict__ h_d,
    float* __restrict__ pooled_res, int* __restrict__ gcnt_res,  // rare-path residue
    float* __restrict__ part, int* __restrict__ pg, int* __restrict__ pc)
{
  const int wv = threadIdx.x >> 6, lane = threadIdx.x & 63;
  const int b = blockIdx.x;
  const int n0 = b * K5_NPB;
  const int n1 = min(n0 + K5_NPB, N_NODES);
  const int g_lo = graph_id[n0], g_hi = graph_id[n1 - 1];

  if (g_hi > g_lo + 1) {
    // rare path (a graph smaller than the block span): per-wave atomic flush
    float acc = 0.f; int cur_g = -1; int cnt = 0;
    for (int i = n0 + wv; i < n1; i += 4) {
      int g = graph_id[i];
      if (g != cur_g) {
        if (cur_g >= 0) {
          atomicAdd(&pooled_res[cur_g * HID + lane], acc);
          if (lane == 0) atomicAdd(&gcnt_res[cur_g], cnt);
        }
        acc = 0.f; cnt = 0; cur_g = g;
      }
      acc += h_d[(size_t)i * HID + lane];
      cnt++;
    }
    if (cur_g >= 0) {
      atomicAdd(&pooled_res[cur_g * HID + lane], acc);
      if (lane == 0) atomicAdd(&gcnt_res[cur_g], cnt);
    }
    if (threadIdx.x < 2) pg[b * 2 + threadIdx.x] = -1;
    return;
  }

  // common path: branchless two-bucket accumulation, no atomics, no fences
  float acc_lo = 0.f, acc_hi = 0.f;
  int c_lo = 0, c_hi = 0;
  for (int i = n0 + wv; i < n1; i += 4) {
    int g = graph_id[i];
    float v = h_d[(size_t)i * HID + lane];
    bool hi = (g != g_lo);
    acc_hi += hi ? v : 0.f;
    acc_lo += hi ? 0.f : v;
    c_hi += hi ? 1 : 0;
    c_lo += hi ? 0 : 1;
  }
  __shared__ float ls[2][4][64];
  __shared__ int lc[2][4];
  ls[0][wv][lane] = acc_lo;
  ls[1][wv][lane] = acc_hi;
  if (lane == 0) { lc[0][wv] = c_lo; lc[1][wv] = c_hi; }
  __syncthreads();
  if (wv < 2) {
    float s = ls[wv][0][lane] + ls[wv][1][lane] + ls[wv][2][lane] + ls[wv][3][lane];
    part[((size_t)b * 2 + wv) * HID + lane] = s;
    if (lane == 0) {
      int cnt = lc[wv][0] + lc[wv][1] + lc[wv][2] + lc[wv][3];
      int gg = (wv == 0) ? g_lo : g_hi;
      if (wv == 1 && (g_hi == g_lo || cnt == 0)) gg = -1;
      pg[b * 2 + wv] = gg;
      pc[b * 2 + wv] = cnt;
    }
  }
}

// ---------------- K6: 16 blocks (one per graph) — reduce own segments + per-graph MLP ----------------
__global__ __launch_bounds__(256) void k6_final(
    const float* __restrict__ part, const int* __restrict__ pg, const int* __restrict__ pc,
    const float* __restrict__ pooled_res, const int* __restrict__ gcnt_res,
    const float* __restrict__ z,
    const float* __restrict__ lin1_w, const float* __restrict__ lin1_b,
    const float* __restrict__ lin2_w, const float* __restrict__ lin2_b,
    float* __restrict__ out)
{
  const int g = blockIdx.x;
  const int tid = threadIdx.x, wv = tid >> 6, lane = tid & 63;
  __shared__ int spg[NSEG], spc[NSEG];
  __shared__ float red[4][HID];
  __shared__ int rc[4];
  __shared__ float cat[2 * HID];

  for (int i = tid; i < NSEG; i += 256) { spg[i] = pg[i]; spc[i] = pc[i]; }
  __syncthreads();

  // each wave sweeps a quarter of the segments; spg[s] is wave-uniform -> no divergence
  float acc = 0.f; int cnt = 0;
  for (int s = wv; s < NSEG; s += 4) {
    if (spg[s] == g) {
      acc += part[(size_t)s * HID + lane];  // coalesced 256-B row, independent iters
      cnt += spc[s];
    }
  }
  red[wv][lane] = acc;
  if (lane == 0) rc[wv] = cnt;
  __syncthreads();

  if (wv == 0) {
    float s = red[0][lane] + red[1][lane] + red[2][lane] + red[3][lane]
            + pooled_res[g * HID + lane];
    int c = rc[0] + rc[1] + rc[2] + rc[3] + gcnt_res[g];
    cat[lane] = s / (float)(c > 0 ? c : 1);
  }
  // z1 = z[g] @ lin1.T (wave 1: 64 threads x 128-FMA)
  if (wv == 1) {
    float s = lin1_b[lane];
    const float* zr = z + g * OUT_F;
    const float* wr = lin1_w + lane * OUT_F;
    for (int k = 0; k < OUT_F; k += 4) {
      float4 zv = *(const float4*)(zr + k);
      float4 wv4 = *(const float4*)(wr + k);
      s = fmaf(zv.x, wv4.x, fmaf(zv.y, wv4.y, fmaf(zv.z, wv4.z, fmaf(zv.w, wv4.w, s))));
    }
    cat[HID + lane] = s;
  }
  __syncthreads();
  if (wv == 0) {
    float s = cat[lane] * lin2_w[lane] + cat[HID + lane] * lin2_w[HID + lane];
#pragma unroll
    for (int off = 32; off; off >>= 1) s += __shfl_xor(s, off, 64);
    if (lane == 0) out[g] = 1.f / (1.f + __expf(-(s + lin2_b[0])));
  }
}

extern "C" void kernel_launch(void* const* d_in, const int* in_sizes, int n_in,
                              void* d_out, int out_size, void* d_ws, size_t ws_size,
                              hipStream_t stream) {
  (void)in_sizes; (void)n_in; (void)out_size; (void)ws_size;
  const float* h      = (const float*)d_in[0];
  const float* z      = (const float*)d_in[1];
  const int*   src    = (const int*)d_in[2];
  const int*   dst    = (const int*)d_in[3];
  const int*   gid    = (const int*)d_in[4];
  const float* fc_w   = (const float*)d_in[5];
  const float* attn_l = (const float*)d_in[6];
  const float* attn_r = (const float*)d_in[7];
  const float* bias   = (const float*)d_in[8];
  const float* lin1_w = (const float*)d_in[9];
  const float* lin1_b = (const float*)d_in[10];
  const float* lin2_w = (const float*)d_in[11];
  const float* lin2_b = (const float*)d_in[12];
  float* out = (float*)d_out;

  // workspace layout (~41 MB)
  float4* csr_w     = (float4*)d_ws;                            // E float4 (12.8 MB)
  unsigned char* feat = (unsigned char*)(csr_w + N_EDGES);      // N*ROW bytes
  float* h_d        = (float*)(feat + (size_t)N_NODES * ROW);   // N*64 fp32
  float* el         = h_d + (size_t)N_NODES * HID;              // N*4
  float* er         = el + (size_t)N_NODES * 4;                 // N*4
  float* part       = er + (size_t)N_NODES * 4;                 // NSEG*64 (~200 KB)
  int* pg           = (int*)(part + (size_t)NSEG * HID);        // NSEG
  int* pc           = pg + NSEG;                                // NSEG
  // --- zeroed region: pooled_res, gcnt_res, deg (contiguous, one memset) ---
  float* pooled_res = (float*)(pc + NSEG);                      // 16*64
  int* gcnt_res     = (int*)(pooled_res + N_GRAPHS * HID);      // 16
  int* deg          = gcnt_res + N_GRAPHS;                      // N+1
  // --- end zeroed region ---
  int* offs         = deg + (N_NODES + 1);                      // N+1
  int* rank         = offs + (N_NODES + 1);                     // E
  int* bsum         = rank + N_EDGES;                           // 49

  size_t zero_bytes = N_GRAPHS * HID * sizeof(float) + N_GRAPHS * sizeof(int)
                    + (N_NODES + 1) * sizeof(int);
  hipMemsetAsync(pooled_res, 0, zero_bytes, stream);

  k0_mfma<<<GB0, 256, 0, stream>>>(h, fc_w, attn_l, attn_r, feat, el, er);
  k1_hist<<<N_EDGES / 256, 256, 0, stream>>>(dst, deg, rank);
  k2a_blocksum<<<SCAN_NB, SCAN_T, 0, stream>>>(deg, bsum);
  k2c_apply<<<SCAN_NB, SCAN_T, 0, stream>>>(deg, bsum, offs);
  k3_edge<<<N_EDGES / 256, 256, 0, stream>>>(src, dst, el, er, offs, rank, csr_w);
  k4_agg<<<N_NODES / 4, 256, 0, stream>>>(offs, csr_w, feat, bias, h_d);
  k5a_partial<<<K5_NB, 256, 0, stream>>>(gid, h_d, pooled_res, gcnt_res, part, pg, pc);
  k6_final<<<N_GRAPHS, 256, 0, stream>>>(part, pg, pc, pooled_res, gcnt_res,
                                         z, lin1_w, lin1_b, lin2_w, lin2_b, out);
}

// Round 13
// 241.200 us; speedup vs baseline: 1.3753x; 1.0313x over previous
//
#include <hip/hip_runtime.h>
#include <math.h>

#define N_NODES 50000
#define N_EDGES 800000
#define N_GRAPHS 16
#define NODE_F 128
#define HID 64
#define OUT_F 128
#define HEADS 3
#define NEG 0.2f
#define FEAT (HEADS*HID)  // 192

typedef float f32x4 __attribute__((ext_vector_type(4)));
typedef float f32x2 __attribute__((ext_vector_type(2)));
typedef short bf16x8 __attribute__((ext_vector_type(8)));

#if defined(__has_builtin)
#if __has_builtin(__builtin_amdgcn_cvt_pk_f32_fp8) && __has_builtin(__builtin_amdgcn_cvt_pk_fp8_f32)
#define USE_FP8 1
#endif
#endif
#ifndef USE_FP8
#define USE_FP8 0
#endif

#if USE_FP8
#define FB 1  // bytes per stored feat element
#else
#define FB 2
#endif
// feat layout: [node][32 pair-groups][8*FB bytes]; group p = dims (2p,2p+1) x 3 heads (6*FB used)
#define GRP (8 * FB)
#define ROW (32 * GRP)

__device__ __forceinline__ ushort f2bf(float x) {
  union { float f; unsigned u; } v; v.f = x;
  unsigned r = v.u + 0x7fff + ((v.u >> 16) & 1);  // round-to-nearest-even
  return (ushort)(r >> 16);
}
__device__ __forceinline__ float bf2f(ushort x) {
  union { unsigned u; float f; } v; v.u = ((unsigned)x) << 16;
  return v.f;
}

// store one feat element: head hh, dim dd
__device__ __forceinline__ void feat_store(unsigned char* base, int n, int hh, int dd, float v) {
  size_t off = (size_t)n * ROW + (dd >> 1) * GRP + ((hh * 2 + (dd & 1)) * FB);
#if USE_FP8
  base[off] = (unsigned char)(__builtin_amdgcn_cvt_pk_fp8_f32(v, 0.f, 0, false) & 0xff);
#else
  *(ushort*)(base + off) = f2bf(v);
#endif
}

// ---------------- K1 fused: [0..3124] histogram+rank | [3125..] fc_w -> fcb bf16 repack ----------------
// fcb fragment order: idx(t,kk,kq,m,j) = (((t*4+kk)*4+kq)*16 + m)*8 + j
#define HB (N_EDGES / 256)  // 3125
__global__ void k1_fused(const int* __restrict__ dst, int* __restrict__ deg,
                         int* __restrict__ rank,
                         const float* __restrict__ fc_w, ushort* __restrict__ fcb) {
  if (blockIdx.x < HB) {
    int e = blockIdx.x * 256 + threadIdx.x;
    rank[e] = atomicAdd(&deg[dst[e]], 1);
    return;
  }
  int i = (blockIdx.x - HB) * 256 + threadIdx.x;  // [0, 6144)
  int col = i >> 5;             // [0,192)
  int kb = (i & 31) * 4;        // k base, multiple of 4
  float4 v = *(const float4*)(fc_w + (size_t)col * NODE_F + kb);
  int t = col >> 4, m = col & 15;
  int kk = kb >> 5, kq = (kb >> 3) & 3, j = kb & 7;
  size_t idx0 = ((((size_t)t * 4 + kk) * 4 + kq) * 16 + m) * 8 + j;
  ushort4 o; o.x = f2bf(v.x); o.y = f2bf(v.y); o.z = f2bf(v.z); o.w = f2bf(v.w);
  *(ushort4*)(fcb + idx0) = o;  // 8-B aligned (j in {0,4})
}

// ---------------- K0: feat = h @ fc_w.T via MFMA; B-frags direct from fcb (no B LDS) ----------------
#define GB0 ((N_NODES + 63) / 64)  // 782
__global__ __launch_bounds__(256) void k0_mfma(
    const float* __restrict__ h, const ushort* __restrict__ fcb,
    const float* __restrict__ attn_l, const float* __restrict__ attn_r,
    unsigned char* __restrict__ feat, float* __restrict__ el, float* __restrict__ er)
{
  __shared__ ushort A[64][136];   // bf16, 272 B row stride (2-way banks = free)
  const int tid = threadIdx.x;
  const int n0 = blockIdx.x * 64;

  for (int i = tid; i < 64 * 32; i += 256) {
    int r = i >> 5, c4 = i & 31;
    if (n0 + r < N_NODES) {
      float4 v = *(const float4*)(h + (size_t)(n0 + r) * NODE_F + c4 * 4);
      unsigned lo = f2bf(v.x) | ((unsigned)f2bf(v.y) << 16);
      unsigned hi = f2bf(v.z) | ((unsigned)f2bf(v.w) << 16);
      *(uint2*)&A[r][c4 * 4] = make_uint2(lo, hi);
    }
  }
  __syncthreads();  // single barrier

  const int lane = tid & 63, wv = tid >> 6;
  const int m = lane & 15, kq = lane >> 4;

  f32x4 acc[12];
#pragma unroll
  for (int t = 0; t < 12; t++) acc[t] = (f32x4){0.f, 0.f, 0.f, 0.f};

#pragma unroll
  for (int kk = 0; kk < 4; kk++) {
    bf16x8 af = *(const bf16x8*)&A[wv * 16 + m][kk * 32 + kq * 8];
#pragma unroll
    for (int t = 0; t < 12; t++) {
      // wave reads 1024 contiguous bytes; fcb is 48 KB -> L1/L2 resident
      const bf16x8 bf = *(const bf16x8*)(fcb + ((((size_t)t * 4 + kk) * 4 + kq) * 16 + m) * 8);
      acc[t] = __builtin_amdgcn_mfma_f32_16x16x32_bf16(af, bf, acc[t], 0, 0, 0);
    }
  }

  const int rbase = n0 + wv * 16 + kq * 4;
#pragma unroll
  for (int t = 0; t < 12; t++) {
    const int hh = t >> 2;              // head
    const int dd = (t & 3) * 16 + m;    // dim within head
#pragma unroll
    for (int reg = 0; reg < 4; reg++) {
      int n = rbase + reg;
      if (n < N_NODES) feat_store(feat, n, hh, dd, acc[t][reg]);
    }
  }

#pragma unroll
  for (int hh = 0; hh < HEADS; hh++) {
    float elv[4] = {0.f, 0.f, 0.f, 0.f};
    float erv[4] = {0.f, 0.f, 0.f, 0.f};
#pragma unroll
    for (int tt = 0; tt < 4; tt++) {
      int t = hh * 4 + tt;
      float al = attn_l[hh * HID + tt * 16 + m];
      float ar = attn_r[hh * HID + tt * 16 + m];
#pragma unroll
      for (int reg = 0; reg < 4; reg++) {
        elv[reg] = fmaf(acc[t][reg], al, elv[reg]);
        erv[reg] = fmaf(acc[t][reg], ar, erv[reg]);
      }
    }
#pragma unroll
    for (int reg = 0; reg < 4; reg++) {
#pragma unroll
      for (int off = 1; off < 16; off <<= 1) {
        elv[reg] += __shfl_xor(elv[reg], off, 64);
        erv[reg] += __shfl_xor(erv[reg], off, 64);
      }
      int n = rbase + reg;
      if (m == 0 && n < N_NODES) {
        el[(size_t)n * 4 + hh] = elv[reg];
        er[(size_t)n * 4 + hh] = erv[reg];
      }
    }
  }
}

// ---------------- K2: scan (block sums, then apply w/ inline block-offset) ----------------
#define SCAN_T 1024
#define SCAN_NB 49  // ceil(50000/1024)

__global__ __launch_bounds__(SCAN_T) void k2a_blocksum(
    const int* __restrict__ deg, int* __restrict__ bsum)
{
  const int tid = threadIdx.x;
  int idx = blockIdx.x * SCAN_T + tid;
  int v = (idx < N_NODES) ? deg[idx] : 0;
#pragma unroll
  for (int off = 32; off; off >>= 1) v += __shfl_xor(v, off, 64);
  __shared__ int ws_[16];
  if ((tid & 63) == 0) ws_[tid >> 6] = v;
  __syncthreads();
  if (tid == 0) {
    int s = 0;
    for (int i = 0; i < 16; i++) s += ws_[i];
    bsum[blockIdx.x] = s;
  }
}

__global__ __launch_bounds__(SCAN_T) void k2c_apply(
    const int* __restrict__ deg, const int* __restrict__ bsum,
    int* __restrict__ offs)
{
  __shared__ int wsum[16], woff[16], bo;
  const int tid = threadIdx.x;
  const int lane = tid & 63, wv = tid >> 6;
  const int idx = blockIdx.x * SCAN_T + tid;
  if (tid < 64) {
    int v = (tid < blockIdx.x) ? bsum[tid] : 0;  // blockIdx <= 48 < 64
#pragma unroll
    for (int off = 32; off; off >>= 1) v += __shfl_xor(v, off, 64);
    if (tid == 0) bo = v;
  }
  int v = (idx < N_NODES) ? deg[idx] : 0;
  int s = v;
#pragma unroll
  for (int off = 1; off < 64; off <<= 1) {
    int t = __shfl_up(s, off, 64);
    if (lane >= off) s += t;
  }
  if (lane == 63) wsum[wv] = s;
  __syncthreads();
  if (tid < 16) {
    int w = wsum[tid];
    int sc = w;
#pragma unroll
    for (int off = 1; off < 16; off <<= 1) {
      int t = __shfl_up(sc, off, 64);
      if (tid >= off) sc += t;
    }
    woff[tid] = sc - w;
  }
  __syncthreads();
  int excl = s - v + woff[wv] + bo;
  if (idx < N_NODES) offs[idx] = excl;
  if (blockIdx.x == 0 && tid == 0) offs[N_NODES] = N_EDGES;
}

// ---------------- K3: edge weights + NO-ATOMIC scatter {w0,w1,w2,byteoff} into CSR ----------------
__global__ __launch_bounds__(256) void k3_edge(
    const int* __restrict__ src, const int* __restrict__ dst,
    const float* __restrict__ el4, const float* __restrict__ er4,
    const int* __restrict__ offs, const int* __restrict__ rank,
    float4* __restrict__ csr_w)
{
  int e = blockIdx.x * 256 + threadIdx.x;  // grid exact E/256
  int s = src[e], d = dst[e];
  int pos = offs[d] + rank[e];
  float4 elv = ((const float4*)el4)[s];
  float4 erv = ((const float4*)er4)[d];
  float e0 = elv.x + erv.x; e0 = e0 > 0.f ? e0 : NEG * e0;
  float e1 = elv.y + erv.y; e1 = e1 > 0.f ? e1 : NEG * e1;
  float e2 = elv.z + erv.z; e2 = e2 > 0.f ? e2 : NEG * e2;
  float4 r;
  r.x = __expf(e0); r.y = __expf(e1); r.z = __expf(e2);
  r.w = __int_as_float(s * ROW);  // byte offset of feat row
  csr_w[pos] = r;
}

// ---------------- K4: wave per node, all heads, single sweep, ONE 8B gather/edge ----------------
__global__ __launch_bounds__(256) void k4_agg(
    const int* __restrict__ offs, const float4* __restrict__ csr_w,
    const unsigned char* __restrict__ feat, const float* __restrict__ bias,
    float* __restrict__ h_d)
{
  __shared__ float4 rec[4][64];  // per-wave staging, 4 KB/block
  const int wv = threadIdx.x >> 6, lane = threadIdx.x & 63;
  const int n = blockIdx.x * 4 + wv;  // grid exact: N/4
  const int lo = offs[n], hi = offs[n + 1];
  const int half = lane >> 5;
  const int d = lane & 31;
  const char* fb = (const char*)feat;

  float a0x = 0.f, a0y = 0.f, a1x = 0.f, a1y = 0.f, a2x = 0.f, a2y = 0.f;
  float s0 = 0.f, s1 = 0.f, s2 = 0.f;

  for (int base = lo; base < hi; base += 64) {
    const int cnt = min(64, hi - base);
    if (lane < cnt) {
      float4 c = csr_w[base + lane];
      rec[wv][lane] = c;
      s0 += c.x; s1 += c.y; s2 += c.z;  // each edge counted once (by its staging lane)
    }
#define K4_BODY(J) do { \
      float4 c = rec[wv][J]; \
      const char* rp = fb + __float_as_int(c.w) + GRP * d; \
      f32x2 f0, f1, f2; \
      if (USE_FP8) { \
        uint2 q = *(const uint2*)rp; \
        f0 = __builtin_amdgcn_cvt_pk_f32_fp8(q.x & 0xffff, false); \
        f1 = __builtin_amdgcn_cvt_pk_f32_fp8(q.x >> 16, false); \
        f2 = __builtin_amdgcn_cvt_pk_f32_fp8(q.y & 0xffff, false); \
      } else { \
        uint4 q = *(const uint4*)rp; \
        f0.x = bf2f((ushort)(q.x & 0xffff)); f0.y = bf2f((ushort)(q.x >> 16)); \
        f1.x = bf2f((ushort)(q.y & 0xffff)); f1.y = bf2f((ushort)(q.y >> 16)); \
        f2.x = bf2f((ushort)(q.z & 0xffff)); f2.y = bf2f((ushort)(q.z >> 16)); \
      } \
      a0x = fmaf(c.x, f0.x, a0x); a0y = fmaf(c.x, f0.y, a0y); \
      a1x = fmaf(c.y, f1.x, a1x); a1y = fmaf(c.y, f1.y, a1y); \
      a2x = fmaf(c.z, f2.x, a2x); a2y = fmaf(c.z, f2.y, a2y); \
    } while (0)
    int j = half;
    for (; j + 2 < cnt; j += 4) { K4_BODY(j); K4_BODY(j + 2); }
    if (j < cnt) K4_BODY(j);
#undef K4_BODY
  }
  // combine the two half-wave edge partitions (same dims, disjoint edges)
  a0x += __shfl_xor(a0x, 32, 64); a0y += __shfl_xor(a0y, 32, 64);
  a1x += __shfl_xor(a1x, 32, 64); a1y += __shfl_xor(a1y, 32, 64);
  a2x += __shfl_xor(a2x, 32, 64); a2y += __shfl_xor(a2y, 32, 64);
#pragma unroll
  for (int off = 32; off; off >>= 1) {
    s0 += __shfl_xor(s0, off, 64);
    s1 += __shfl_xor(s1, off, 64);
    s2 += __shfl_xor(s2, off, 64);
  }
  const float i0 = s0 > 0.f ? 1.f / s0 : 0.f;
  const float i1 = s1 > 0.f ? 1.f / s1 : 0.f;
  const float i2 = s2 > 0.f ? 1.f / s2 : 0.f;
  if (half == 0) {
    float2 b0 = *(const float2*)(bias + 2 * d);
    float2 b1 = *(const float2*)(bias + HID + 2 * d);
    float2 b2 = *(const float2*)(bias + 2 * HID + 2 * d);
    float2 o;
    o.x = (fmaf(a0x, i0, b0.x) + fmaf(a1x, i1, b1.x) + fmaf(a2x, i2, b2.x)) * (1.f / 3.f);
    o.y = (fmaf(a0y, i0, b0.y) + fmaf(a1y, i1, b1.y) + fmaf(a2y, i2, b2.y)) * (1.f / 3.f);
    *(float2*)(h_d + (size_t)n * HID + 2 * d) = o;
  }
}

// ---------------- K5a: atomic-free block partials (sorted graph_id, span<=2 fast path) ----------------
#define K5_NPB 128
#define K5_NB ((N_NODES + K5_NPB - 1) / K5_NPB)  // 391
#define NSEG (K5_NB * 2)                         // 782
__global__ __launch_bounds__(256) void k5a_partial(
    const int* __restrict__ graph_id, const float* __restrict__ h_d,
    float* __restrict__ pooled_res, int* __restrict__ gcnt_res,  // rare-path residue
    float* __restrict__ part, int* __restrict__ pg, int* __restrict__ pc)
{
  const int wv = threadIdx.x >> 6, lane = threadIdx.x & 63;
  const int b = blockIdx.x;
  const int n0 = b * K5_NPB;
  const int n1 = min(n0 + K5_NPB, N_NODES);
  const int g_lo = graph_id[n0], g_hi = graph_id[n1 - 1];

  if (g_hi > g_lo + 1) {
    // rare path (a graph smaller than the block span): per-wave atomic flush
    float acc = 0.f; int cur_g = -1; int cnt = 0;
    for (int i = n0 + wv; i < n1; i += 4) {
      int g = graph_id[i];
      if (g != cur_g) {
        if (cur_g >= 0) {
          atomicAdd(&pooled_res[cur_g * HID + lane], acc);
          if (lane == 0) atomicAdd(&gcnt_res[cur_g], cnt);
        }
        acc = 0.f; cnt = 0; cur_g = g;
      }
      acc += h_d[(size_t)i * HID + lane];
      cnt++;
    }
    if (cur_g >= 0) {
      atomicAdd(&pooled_res[cur_g * HID + lane], acc);
      if (lane == 0) atomicAdd(&gcnt_res[cur_g], cnt);
    }
    if (threadIdx.x < 2) pg[b * 2 + threadIdx.x] = -1;
    return;
  }

  // common path: branchless two-bucket accumulation, no atomics, no fences
  float acc_lo = 0.f, acc_hi = 0.f;
  int c_lo = 0, c_hi = 0;
  for (int i = n0 + wv; i < n1; i += 4) {
    int g = graph_id[i];
    float v = h_d[(size_t)i * HID + lane];
    bool hi = (g != g_lo);
    acc_hi += hi ? v : 0.f;
    acc_lo += hi ? 0.f : v;
    c_hi += hi ? 1 : 0;
    c_lo += hi ? 0 : 1;
  }
  __shared__ float ls[2][4][64];
  __shared__ int lc[2][4];
  ls[0][wv][lane] = acc_lo;
  ls[1][wv][lane] = acc_hi;
  if (lane == 0) { lc[0][wv] = c_lo; lc[1][wv] = c_hi; }
  __syncthreads();
  if (wv < 2) {
    float s = ls[wv][0][lane] + ls[wv][1][lane] + ls[wv][2][lane] + ls[wv][3][lane];
    part[((size_t)b * 2 + wv) * HID + lane] = s;
    if (lane == 0) {
      int cnt = lc[wv][0] + lc[wv][1] + lc[wv][2] + lc[wv][3];
      int gg = (wv == 0) ? g_lo : g_hi;
      if (wv == 1 && (g_hi == g_lo || cnt == 0)) gg = -1;
      pg[b * 2 + wv] = gg;
      pc[b * 2 + wv] = cnt;
    }
  }
}

// ---------------- K6: 16 blocks (one per graph) — reduce own segments + per-graph MLP ----------------
__global__ __launch_bounds__(256) void k6_final(
    const float* __restrict__ part, const int* __restrict__ pg, const int* __restrict__ pc,
    const float* __restrict__ pooled_res, const int* __restrict__ gcnt_res,
    const float* __restrict__ z,
    const float* __restrict__ lin1_w, const float* __restrict__ lin1_b,
    const float* __restrict__ lin2_w, const float* __restrict__ lin2_b,
    float* __restrict__ out)
{
  const int g = blockIdx.x;
  const int tid = threadIdx.x, wv = tid >> 6, lane = tid & 63;
  __shared__ int spg[NSEG], spc[NSEG];
  __shared__ float red[4][HID];
  __shared__ int rc[4];
  __shared__ float cat[2 * HID];

  for (int i = tid; i < NSEG; i += 256) { spg[i] = pg[i]; spc[i] = pc[i]; }
  __syncthreads();

  // each wave sweeps a quarter of the segments; spg[s] is wave-uniform -> no divergence
  float acc = 0.f; int cnt = 0;
  for (int s = wv; s < NSEG; s += 4) {
    if (spg[s] == g) {
      acc += part[(size_t)s * HID + lane];  // coalesced 256-B row, independent iters
      cnt += spc[s];
    }
  }
  red[wv][lane] = acc;
  if (lane == 0) rc[wv] = cnt;
  __syncthreads();

  if (wv == 0) {
    float s = red[0][lane] + red[1][lane] + red[2][lane] + red[3][lane]
            + pooled_res[g * HID + lane];
    int c = rc[0] + rc[1] + rc[2] + rc[3] + gcnt_res[g];
    cat[lane] = s / (float)(c > 0 ? c : 1);
  }
  // z1 = z[g] @ lin1.T (wave 1: 64 threads x 128-FMA)
  if (wv == 1) {
    float s = lin1_b[lane];
    const float* zr = z + g * OUT_F;
    const float* wr = lin1_w + lane * OUT_F;
    for (int k = 0; k < OUT_F; k += 4) {
      float4 zv = *(const float4*)(zr + k);
      float4 wv4 = *(const float4*)(wr + k);
      s = fmaf(zv.x, wv4.x, fmaf(zv.y, wv4.y, fmaf(zv.z, wv4.z, fmaf(zv.w, wv4.w, s))));
    }
    cat[HID + lane] = s;
  }
  __syncthreads();
  if (wv == 0) {
    float s = cat[lane] * lin2_w[lane] + cat[HID + lane] * lin2_w[HID + lane];
#pragma unroll
    for (int off = 32; off; off >>= 1) s += __shfl_xor(s, off, 64);
    if (lane == 0) out[g] = 1.f / (1.f + __expf(-(s + lin2_b[0])));
  }
}

extern "C" void kernel_launch(void* const* d_in, const int* in_sizes, int n_in,
                              void* d_out, int out_size, void* d_ws, size_t ws_size,
                              hipStream_t stream) {
  (void)in_sizes; (void)n_in; (void)out_size; (void)ws_size;
  const float* h      = (const float*)d_in[0];
  const float* z      = (const float*)d_in[1];
  const int*   src    = (const int*)d_in[2];
  const int*   dst    = (const int*)d_in[3];
  const int*   gid    = (const int*)d_in[4];
  const float* fc_w   = (const float*)d_in[5];
  const float* attn_l = (const float*)d_in[6];
  const float* attn_r = (const float*)d_in[7];
  const float* bias   = (const float*)d_in[8];
  const float* lin1_w = (const float*)d_in[9];
  const float* lin1_b = (const float*)d_in[10];
  const float* lin2_w = (const float*)d_in[11];
  const float* lin2_b = (const float*)d_in[12];
  float* out = (float*)d_out;

  // workspace layout (~41 MB)
  float4* csr_w     = (float4*)d_ws;                            // E float4 (12.8 MB)
  unsigned char* feat = (unsigned char*)(csr_w + N_EDGES);      // N*ROW bytes
  float* h_d        = (float*)(feat + (size_t)N_NODES * ROW);   // N*64 fp32
  float* el         = h_d + (size_t)N_NODES * HID;              // N*4
  float* er         = el + (size_t)N_NODES * 4;                 // N*4
  float* part       = er + (size_t)N_NODES * 4;                 // NSEG*64 (~200 KB)
  int* pg           = (int*)(part + (size_t)NSEG * HID);        // NSEG
  int* pc           = pg + NSEG;                                // NSEG
  ushort* fcb       = (ushort*)(pc + NSEG);                     // 192*128 bf16 (48 KB)
  // --- zeroed region: pooled_res, gcnt_res, deg (contiguous, one memset) ---
  float* pooled_res = (float*)(fcb + 192 * NODE_F);             // 16*64
  int* gcnt_res     = (int*)(pooled_res + N_GRAPHS * HID);      // 16
  int* deg          = gcnt_res + N_GRAPHS;                      // N+1
  // --- end zeroed region ---
  int* offs         = deg + (N_NODES + 1);                      // N+1
  int* rank         = offs + (N_NODES + 1);                     // E
  int* bsum         = rank + N_EDGES;                           // 49

  size_t zero_bytes = N_GRAPHS * HID * sizeof(float) + N_GRAPHS * sizeof(int)
                    + (N_NODES + 1) * sizeof(int);
  hipMemsetAsync(pooled_res, 0, zero_bytes, stream);

  k1_fused<<<HB + 24, 256, 0, stream>>>(dst, deg, rank, fc_w, fcb);
  k0_mfma<<<GB0, 256, 0, stream>>>(h, fcb, attn_l, attn_r, feat, el, er);
  k2a_blocksum<<<SCAN_NB, SCAN_T, 0, stream>>>(deg, bsum);
  k2c_apply<<<SCAN_NB, SCAN_T, 0, stream>>>(deg, bsum, offs);
  k3_edge<<<N_EDGES / 256, 256, 0, stream>>>(src, dst, el, er, offs, rank, csr_w);
  k4_agg<<<N_NODES / 4, 256, 0, stream>>>(offs, csr_w, feat, bias, h_d);
  k5a_partial<<<K5_NB, 256, 0, stream>>>(gid, h_d, pooled_res, gcnt_res, part, pg, pc);
  k6_final<<<N_GRAPHS, 256, 0, stream>>>(part, pg, pc, pooled_res, gcnt_res,
                                         z, lin1_w, lin1_b, lin2_w, lin2_b, out);
}

// Round 14
// 233.644 us; speedup vs baseline: 1.4198x; 1.0323x over previous
//
#include <hip/hip_runtime.h>
#include <math.h>

#define N_NODES 50000
#define N_EDGES 800000
#define N_GRAPHS 16
#define NODE_F 128
#define HID 64
#define OUT_F 128
#define HEADS 3
#define NEG 0.2f
#define FEAT (HEADS*HID)  // 192

typedef float f32x4 __attribute__((ext_vector_type(4)));
typedef float f32x2 __attribute__((ext_vector_type(2)));
typedef short bf16x8 __attribute__((ext_vector_type(8)));

#if defined(__has_builtin)
#if __has_builtin(__builtin_amdgcn_cvt_pk_f32_fp8) && __has_builtin(__builtin_amdgcn_cvt_pk_fp8_f32)
#define USE_FP8 1
#endif
#endif
#ifndef USE_FP8
#define USE_FP8 0
#endif

#if USE_FP8
#define FB 1  // bytes per stored feat element
#else
#define FB 2
#endif
// feat layout: [node][32 pair-groups][8*FB bytes]; group p = dims (2p,2p+1) x 3 heads (6*FB used)
#define GRP (8 * FB)
#define ROW (32 * GRP)

__device__ __forceinline__ ushort f2bf(float x) {
  union { float f; unsigned u; } v; v.f = x;
  unsigned r = v.u + 0x7fff + ((v.u >> 16) & 1);  // round-to-nearest-even
  return (ushort)(r >> 16);
}
__device__ __forceinline__ float bf2f(ushort x) {
  union { unsigned u; float f; } v; v.u = ((unsigned)x) << 16;
  return v.f;
}

// store one feat element: head hh, dim dd
__device__ __forceinline__ void feat_store(unsigned char* base, int n, int hh, int dd, float v) {
  size_t off = (size_t)n * ROW + (dd >> 1) * GRP + ((hh * 2 + (dd & 1)) * FB);
#if USE_FP8
  base[off] = (unsigned char)(__builtin_amdgcn_cvt_pk_fp8_f32(v, 0.f, 0, false) & 0xff);
#else
  *(ushort*)(base + off) = f2bf(v);
#endif
}

// ---------------- KPREP: [0..23] fc_w -> fcb bf16 fragment repack | [24..223] zero counters ----------------
// fcb fragment order: idx(t,kk,kq,m,j) = (((t*4+kk)*4+kq)*16 + m)*8 + j
#define ZERO_INTS (N_GRAPHS * HID + N_GRAPHS + (N_NODES + 1))  // pooled_res, gcnt_res, deg
#define ZB ((ZERO_INTS + 255) / 256)  // 200
__global__ void kprep(const float* __restrict__ fc_w, ushort* __restrict__ fcb,
                      int* __restrict__ zbase) {
  if (blockIdx.x >= 24) {
    int i = (blockIdx.x - 24) * 256 + threadIdx.x;
    if (i < ZERO_INTS) zbase[i] = 0;
    return;
  }
  int i = blockIdx.x * 256 + threadIdx.x;  // [0, 6144)
  int col = i >> 5;             // [0,192)
  int kb = (i & 31) * 4;        // k base, multiple of 4
  float4 v = *(const float4*)(fc_w + (size_t)col * NODE_F + kb);
  int t = col >> 4, m = col & 15;
  int kk = kb >> 5, kq = (kb >> 3) & 3, j = kb & 7;
  size_t idx0 = ((((size_t)t * 4 + kk) * 4 + kq) * 16 + m) * 8 + j;
  ushort4 o; o.x = f2bf(v.x); o.y = f2bf(v.y); o.z = f2bf(v.z); o.w = f2bf(v.w);
  *(ushort4*)(fcb + idx0) = o;  // 8-B aligned (j in {0,4})
}

// ---------------- K01 fused: [blocks < GB0] MFMA GEMM (17 KB LDS, 1 barrier) | [rest] hist+rank ----------------
// R9's fusion failed at 32 KB LDS + 8 barriers; now hist blocks are wave-limited, not LDS-limited,
// and hist atomic stalls co-schedule with GEMM MFMA (m114).
#define GB0 ((N_NODES + 63) / 64)  // 782
#define HB (N_EDGES / 256)         // 3125
__global__ __launch_bounds__(256) void k01_fused(
    const float* __restrict__ h, const ushort* __restrict__ fcb,
    const float* __restrict__ attn_l, const float* __restrict__ attn_r,
    const int* __restrict__ dst,
    unsigned char* __restrict__ feat, float* __restrict__ el, float* __restrict__ er,
    int* __restrict__ deg, int* __restrict__ rank)
{
  __shared__ ushort A[64][136];   // bf16, 272 B row stride (2-way banks = free)
  const int tid = threadIdx.x;

  if (blockIdx.x >= GB0) {
    int e = (blockIdx.x - GB0) * 256 + tid;  // exact: HB*256 = E
    rank[e] = atomicAdd(&deg[dst[e]], 1);
    return;
  }

  const int n0 = blockIdx.x * 64;
  for (int i = tid; i < 64 * 32; i += 256) {
    int r = i >> 5, c4 = i & 31;
    if (n0 + r < N_NODES) {
      float4 v = *(const float4*)(h + (size_t)(n0 + r) * NODE_F + c4 * 4);
      unsigned lo = f2bf(v.x) | ((unsigned)f2bf(v.y) << 16);
      unsigned hi = f2bf(v.z) | ((unsigned)f2bf(v.w) << 16);
      *(uint2*)&A[r][c4 * 4] = make_uint2(lo, hi);
    }
  }
  __syncthreads();  // single barrier

  const int lane = tid & 63, wv = tid >> 6;
  const int m = lane & 15, kq = lane >> 4;

  f32x4 acc[12];
#pragma unroll
  for (int t = 0; t < 12; t++) acc[t] = (f32x4){0.f, 0.f, 0.f, 0.f};

#pragma unroll
  for (int kk = 0; kk < 4; kk++) {
    bf16x8 af = *(const bf16x8*)&A[wv * 16 + m][kk * 32 + kq * 8];
#pragma unroll
    for (int t = 0; t < 12; t++) {
      // wave reads 1024 contiguous bytes; fcb is 48 KB -> L1/L2 resident
      const bf16x8 bf = *(const bf16x8*)(fcb + ((((size_t)t * 4 + kk) * 4 + kq) * 16 + m) * 8);
      acc[t] = __builtin_amdgcn_mfma_f32_16x16x32_bf16(af, bf, acc[t], 0, 0, 0);
    }
  }

  const int rbase = n0 + wv * 16 + kq * 4;
#pragma unroll
  for (int t = 0; t < 12; t++) {
    const int hh = t >> 2;              // head
    const int dd = (t & 3) * 16 + m;    // dim within head
#pragma unroll
    for (int reg = 0; reg < 4; reg++) {
      int n = rbase + reg;
      if (n < N_NODES) feat_store(feat, n, hh, dd, acc[t][reg]);
    }
  }

#pragma unroll
  for (int hh = 0; hh < HEADS; hh++) {
    float elv[4] = {0.f, 0.f, 0.f, 0.f};
    float erv[4] = {0.f, 0.f, 0.f, 0.f};
#pragma unroll
    for (int tt = 0; tt < 4; tt++) {
      int t = hh * 4 + tt;
      float al = attn_l[hh * HID + tt * 16 + m];
      float ar = attn_r[hh * HID + tt * 16 + m];
#pragma unroll
      for (int reg = 0; reg < 4; reg++) {
        elv[reg] = fmaf(acc[t][reg], al, elv[reg]);
        erv[reg] = fmaf(acc[t][reg], ar, erv[reg]);
      }
    }
#pragma unroll
    for (int reg = 0; reg < 4; reg++) {
#pragma unroll
      for (int off = 1; off < 16; off <<= 1) {
        elv[reg] += __shfl_xor(elv[reg], off, 64);
        erv[reg] += __shfl_xor(erv[reg], off, 64);
      }
      int n = rbase + reg;
      if (m == 0 && n < N_NODES) {
        el[(size_t)n * 4 + hh] = elv[reg];
        er[(size_t)n * 4 + hh] = erv[reg];
      }
    }
  }
}

// ---------------- K2: scan (block sums, then apply w/ inline block-offset) ----------------
#define SCAN_T 1024
#define SCAN_NB 49  // ceil(50000/1024)

__global__ __launch_bounds__(SCAN_T) void k2a_blocksum(
    const int* __restrict__ deg, int* __restrict__ bsum)
{
  const int tid = threadIdx.x;
  int idx = blockIdx.x * SCAN_T + tid;
  int v = (idx < N_NODES) ? deg[idx] : 0;
#pragma unroll
  for (int off = 32; off; off >>= 1) v += __shfl_xor(v, off, 64);
  __shared__ int ws_[16];
  if ((tid & 63) == 0) ws_[tid >> 6] = v;
  __syncthreads();
  if (tid == 0) {
    int s = 0;
    for (int i = 0; i < 16; i++) s += ws_[i];
    bsum[blockIdx.x] = s;
  }
}

__global__ __launch_bounds__(SCAN_T) void k2c_apply(
    const int* __restrict__ deg, const int* __restrict__ bsum,
    int* __restrict__ offs)
{
  __shared__ int wsum[16], woff[16], bo;
  const int tid = threadIdx.x;
  const int lane = tid & 63, wv = tid >> 6;
  const int idx = blockIdx.x * SCAN_T + tid;
  if (tid < 64) {
    int v = (tid < blockIdx.x) ? bsum[tid] : 0;  // blockIdx <= 48 < 64
#pragma unroll
    for (int off = 32; off; off >>= 1) v += __shfl_xor(v, off, 64);
    if (tid == 0) bo = v;
  }
  int v = (idx < N_NODES) ? deg[idx] : 0;
  int s = v;
#pragma unroll
  for (int off = 1; off < 64; off <<= 1) {
    int t = __shfl_up(s, off, 64);
    if (lane >= off) s += t;
  }
  if (lane == 63) wsum[wv] = s;
  __syncthreads();
  if (tid < 16) {
    int w = wsum[tid];
    int sc = w;
#pragma unroll
    for (int off = 1; off < 16; off <<= 1) {
      int t = __shfl_up(sc, off, 64);
      if (tid >= off) sc += t;
    }
    woff[tid] = sc - w;
  }
  __syncthreads();
  int excl = s - v + woff[wv] + bo;
  if (idx < N_NODES) offs[idx] = excl;
  if (blockIdx.x == 0 && tid == 0) offs[N_NODES] = N_EDGES;
}

// ---------------- K3: edge weights + NO-ATOMIC scatter {w0,w1,w2,byteoff} into CSR ----------------
__global__ __launch_bounds__(256) void k3_edge(
    const int* __restrict__ src, const int* __restrict__ dst,
    const float* __restrict__ el4, const float* __restrict__ er4,
    const int* __restrict__ offs, const int* __restrict__ rank,
    float4* __restrict__ csr_w)
{
  int e = blockIdx.x * 256 + threadIdx.x;  // grid exact E/256
  int s = src[e], d = dst[e];
  int pos = offs[d] + rank[e];
  float4 elv = ((const float4*)el4)[s];
  float4 erv = ((const float4*)er4)[d];
  float e0 = elv.x + erv.x; e0 = e0 > 0.f ? e0 : NEG * e0;
  float e1 = elv.y + erv.y; e1 = e1 > 0.f ? e1 : NEG * e1;
  float e2 = elv.z + erv.z; e2 = e2 > 0.f ? e2 : NEG * e2;
  float4 r;
  r.x = __expf(e0); r.y = __expf(e1); r.z = __expf(e2);
  r.w = __int_as_float(s * ROW);  // byte offset of feat row
  csr_w[pos] = r;
}

// ---------------- K4: wave per node, all heads, single sweep, ONE 8B gather/edge ----------------
__global__ __launch_bounds__(256) void k4_agg(
    const int* __restrict__ offs, const float4* __restrict__ csr_w,
    const unsigned char* __restrict__ feat, const float* __restrict__ bias,
    float* __restrict__ h_d)
{
  __shared__ float4 rec[4][64];  // per-wave staging, 4 KB/block
  const int wv = threadIdx.x >> 6, lane = threadIdx.x & 63;
  const int n = blockIdx.x * 4 + wv;  // grid exact: N/4
  const int lo = offs[n], hi = offs[n + 1];
  const int half = lane >> 5;
  const int d = lane & 31;
  const char* fb = (const char*)feat;

  float a0x = 0.f, a0y = 0.f, a1x = 0.f, a1y = 0.f, a2x = 0.f, a2y = 0.f;
  float s0 = 0.f, s1 = 0.f, s2 = 0.f;

  for (int base = lo; base < hi; base += 64) {
    const int cnt = min(64, hi - base);
    if (lane < cnt) {
      float4 c = csr_w[base + lane];
      rec[wv][lane] = c;
      s0 += c.x; s1 += c.y; s2 += c.z;  // each edge counted once (by its staging lane)
    }
#define K4_BODY(J) do { \
      float4 c = rec[wv][J]; \
      const char* rp = fb + __float_as_int(c.w) + GRP * d; \
      f32x2 f0, f1, f2; \
      if (USE_FP8) { \
        uint2 q = *(const uint2*)rp; \
        f0 = __builtin_amdgcn_cvt_pk_f32_fp8(q.x & 0xffff, false); \
        f1 = __builtin_amdgcn_cvt_pk_f32_fp8(q.x >> 16, false); \
        f2 = __builtin_amdgcn_cvt_pk_f32_fp8(q.y & 0xffff, false); \
      } else { \
        uint4 q = *(const uint4*)rp; \
        f0.x = bf2f((ushort)(q.x & 0xffff)); f0.y = bf2f((ushort)(q.x >> 16)); \
        f1.x = bf2f((ushort)(q.y & 0xffff)); f1.y = bf2f((ushort)(q.y >> 16)); \
        f2.x = bf2f((ushort)(q.z & 0xffff)); f2.y = bf2f((ushort)(q.z >> 16)); \
      } \
      a0x = fmaf(c.x, f0.x, a0x); a0y = fmaf(c.x, f0.y, a0y); \
      a1x = fmaf(c.y, f1.x, a1x); a1y = fmaf(c.y, f1.y, a1y); \
      a2x = fmaf(c.z, f2.x, a2x); a2y = fmaf(c.z, f2.y, a2y); \
    } while (0)
    int j = half;
    for (; j + 2 < cnt; j += 4) { K4_BODY(j); K4_BODY(j + 2); }
    if (j < cnt) K4_BODY(j);
#undef K4_BODY
  }
  // combine the two half-wave edge partitions (same dims, disjoint edges)
  a0x += __shfl_xor(a0x, 32, 64); a0y += __shfl_xor(a0y, 32, 64);
  a1x += __shfl_xor(a1x, 32, 64); a1y += __shfl_xor(a1y, 32, 64);
  a2x += __shfl_xor(a2x, 32, 64); a2y += __shfl_xor(a2y, 32, 64);
#pragma unroll
  for (int off = 32; off; off >>= 1) {
    s0 += __shfl_xor(s0, off, 64);
    s1 += __shfl_xor(s1, off, 64);
    s2 += __shfl_xor(s2, off, 64);
  }
  const float i0 = s0 > 0.f ? 1.f / s0 : 0.f;
  const float i1 = s1 > 0.f ? 1.f / s1 : 0.f;
  const float i2 = s2 > 0.f ? 1.f / s2 : 0.f;
  if (half == 0) {
    float2 b0 = *(const float2*)(bias + 2 * d);
    float2 b1 = *(const float2*)(bias + HID + 2 * d);
    float2 b2 = *(const float2*)(bias + 2 * HID + 2 * d);
    float2 o;
    o.x = (fmaf(a0x, i0, b0.x) + fmaf(a1x, i1, b1.x) + fmaf(a2x, i2, b2.x)) * (1.f / 3.f);
    o.y = (fmaf(a0y, i0, b0.y) + fmaf(a1y, i1, b1.y) + fmaf(a2y, i2, b2.y)) * (1.f / 3.f);
    *(float2*)(h_d + (size_t)n * HID + 2 * d) = o;
  }
}

// ---------------- K5a: atomic-free block partials (sorted graph_id, span<=2 fast path) ----------------
#define K5_NPB 128
#define K5_NB ((N_NODES + K5_NPB - 1) / K5_NPB)  // 391
#define NSEG (K5_NB * 2)                         // 782
__global__ __launch_bounds__(256) void k5a_partial(
    const int* __restrict__ graph_id, const float* __restrict__ h_d,
    float* __restrict__ pooled_res, int* __restrict__ gcnt_res,  // rare-path residue
    float* __restrict__ part, int* __restrict__ pg, int* __restrict__ pc)
{
  const int wv = threadIdx.x >> 6, lane = threadIdx.x & 63;
  const int b = blockIdx.x;
  const int n0 = b * K5_NPB;
  const int n1 = min(n0 + K5_NPB, N_NODES);
  const int g_lo = graph_id[n0], g_hi = graph_id[n1 - 1];

  if (g_hi > g_lo + 1) {
    // rare path (a graph smaller than the block span): per-wave atomic flush
    float acc = 0.f; int cur_g = -1; int cnt = 0;
    for (int i = n0 + wv; i < n1; i += 4) {
      int g = graph_id[i];
      if (g != cur_g) {
        if (cur_g >= 0) {
          atomicAdd(&pooled_res[cur_g * HID + lane], acc);
          if (lane == 0) atomicAdd(&gcnt_res[cur_g], cnt);
        }
        acc = 0.f; cnt = 0; cur_g = g;
      }
      acc += h_d[(size_t)i * HID + lane];
      cnt++;
    }
    if (cur_g >= 0) {
      atomicAdd(&pooled_res[cur_g * HID + lane], acc);
      if (lane == 0) atomicAdd(&gcnt_res[cur_g], cnt);
    }
    if (threadIdx.x < 2) pg[b * 2 + threadIdx.x] = -1;
    return;
  }

  // common path: branchless two-bucket accumulation, no atomics, no fences
  float acc_lo = 0.f, acc_hi = 0.f;
  int c_lo = 0, c_hi = 0;
  for (int i = n0 + wv; i < n1; i += 4) {
    int g = graph_id[i];
    float v = h_d[(size_t)i * HID + lane];
    bool hi = (g != g_lo);
    acc_hi += hi ? v : 0.f;
    acc_lo += hi ? 0.f : v;
    c_hi += hi ? 1 : 0;
    c_lo += hi ? 0 : 1;
  }
  __shared__ float ls[2][4][64];
  __shared__ int lc[2][4];
  ls[0][wv][lane] = acc_lo;
  ls[1][wv][lane] = acc_hi;
  if (lane == 0) { lc[0][wv] = c_lo; lc[1][wv] = c_hi; }
  __syncthreads();
  if (wv < 2) {
    float s = ls[wv][0][lane] + ls[wv][1][lane] + ls[wv][2][lane] + ls[wv][3][lane];
    part[((size_t)b * 2 + wv) * HID + lane] = s;
    if (lane == 0) {
      int cnt = lc[wv][0] + lc[wv][1] + lc[wv][2] + lc[wv][3];
      int gg = (wv == 0) ? g_lo : g_hi;
      if (wv == 1 && (g_hi == g_lo || cnt == 0)) gg = -1;
      pg[b * 2 + wv] = gg;
      pc[b * 2 + wv] = cnt;
    }
  }
}

// ---------------- K6: 16 blocks (one per graph) — reduce own segments + per-graph MLP ----------------
__global__ __launch_bounds__(256) void k6_final(
    const float* __restrict__ part, const int* __restrict__ pg, const int* __restrict__ pc,
    const float* __restrict__ pooled_res, const int* __restrict__ gcnt_res,
    const float* __restrict__ z,
    const float* __restrict__ lin1_w, const float* __restrict__ lin1_b,
    const float* __restrict__ lin2_w, const float* __restrict__ lin2_b,
    float* __restrict__ out)
{
  const int g = blockIdx.x;
  const int tid = threadIdx.x, wv = tid >> 6, lane = tid & 63;
  __shared__ int spg[NSEG], spc[NSEG];
  __shared__ float red[4][HID];
  __shared__ int rc[4];
  __shared__ float cat[2 * HID];

  for (int i = tid; i < NSEG; i += 256) { spg[i] = pg[i]; spc[i] = pc[i]; }
  __syncthreads();

  // each wave sweeps a quarter of the segments; spg[s] is wave-uniform -> no divergence
  float acc = 0.f; int cnt = 0;
  for (int s = wv; s < NSEG; s += 4) {
    if (spg[s] == g) {
      acc += part[(size_t)s * HID + lane];  // coalesced 256-B row, independent iters
      cnt += spc[s];
    }
  }
  red[wv][lane] = acc;
  if (lane == 0) rc[wv] = cnt;
  __syncthreads();

  if (wv == 0) {
    float s = red[0][lane] + red[1][lane] + red[2][lane] + red[3][lane]
            + pooled_res[g * HID + lane];
    int c = rc[0] + rc[1] + rc[2] + rc[3] + gcnt_res[g];
    cat[lane] = s / (float)(c > 0 ? c : 1);
  }
  // z1 = z[g] @ lin1.T (wave 1: 64 threads x 128-FMA)
  if (wv == 1) {
    float s = lin1_b[lane];
    const float* zr = z + g * OUT_F;
    const float* wr = lin1_w + lane * OUT_F;
    for (int k = 0; k < OUT_F; k += 4) {
      float4 zv = *(const float4*)(zr + k);
      float4 wv4 = *(const float4*)(wr + k);
      s = fmaf(zv.x, wv4.x, fmaf(zv.y, wv4.y, fmaf(zv.z, wv4.z, fmaf(zv.w, wv4.w, s))));
    }
    cat[HID + lane] = s;
  }
  __syncthreads();
  if (wv == 0) {
    float s = cat[lane] * lin2_w[lane] + cat[HID + lane] * lin2_w[HID + lane];
#pragma unroll
    for (int off = 32; off; off >>= 1) s += __shfl_xor(s, off, 64);
    if (lane == 0) out[g] = 1.f / (1.f + __expf(-(s + lin2_b[0])));
  }
}

extern "C" void kernel_launch(void* const* d_in, const int* in_sizes, int n_in,
                              void* d_out, int out_size, void* d_ws, size_t ws_size,
                              hipStream_t stream) {
  (void)in_sizes; (void)n_in; (void)out_size; (void)ws_size;
  const float* h      = (const float*)d_in[0];
  const float* z      = (const float*)d_in[1];
  const int*   src    = (const int*)d_in[2];
  const int*   dst    = (const int*)d_in[3];
  const int*   gid    = (const int*)d_in[4];
  const float* fc_w   = (const float*)d_in[5];
  const float* attn_l = (const float*)d_in[6];
  const float* attn_r = (const float*)d_in[7];
  const float* bias   = (const float*)d_in[8];
  const float* lin1_w = (const float*)d_in[9];
  const float* lin1_b = (const float*)d_in[10];
  const float* lin2_w = (const float*)d_in[11];
  const float* lin2_b = (const float*)d_in[12];
  float* out = (float*)d_out;

  // workspace layout (~41 MB)
  float4* csr_w     = (float4*)d_ws;                            // E float4 (12.8 MB)
  unsigned char* feat = (unsigned char*)(csr_w + N_EDGES);      // N*ROW bytes
  float* h_d        = (float*)(feat + (size_t)N_NODES * ROW);   // N*64 fp32
  float* el         = h_d + (size_t)N_NODES * HID;              // N*4
  float* er         = el + (size_t)N_NODES * 4;                 // N*4
  float* part       = er + (size_t)N_NODES * 4;                 // NSEG*64 (~200 KB)
  int* pg           = (int*)(part + (size_t)NSEG * HID);        // NSEG
  int* pc           = pg + NSEG;                                // NSEG
  ushort* fcb       = (ushort*)(pc + NSEG);                     // 192*128 bf16 (48 KB)
  // --- zeroed region (by kprep): pooled_res, gcnt_res, deg (contiguous) ---
  float* pooled_res = (float*)(fcb + 192 * NODE_F);             // 16*64
  int* gcnt_res     = (int*)(pooled_res + N_GRAPHS * HID);      // 16
  int* deg          = gcnt_res + N_GRAPHS;                      // N+1
  // --- end zeroed region ---
  int* offs         = deg + (N_NODES + 1);                      // N+1
  int* rank         = offs + (N_NODES + 1);                     // E
  int* bsum         = rank + N_EDGES;                           // 49

  kprep<<<24 + ZB, 256, 0, stream>>>(fc_w, fcb, (int*)pooled_res);
  k01_fused<<<GB0 + HB, 256, 0, stream>>>(h, fcb, attn_l, attn_r, dst,
                                          feat, el, er, deg, rank);
  k2a_blocksum<<<SCAN_NB, SCAN_T, 0, stream>>>(deg, bsum);
  k2c_apply<<<SCAN_NB, SCAN_T, 0, stream>>>(deg, bsum, offs);
  k3_edge<<<N_EDGES / 256, 256, 0, stream>>>(src, dst, el, er, offs, rank, csr_w);
  k4_agg<<<N_NODES / 4, 256, 0, stream>>>(offs, csr_w, feat, bias, h_d);
  k5a_partial<<<K5_NB, 256, 0, stream>>>(gid, h_d, pooled_res, gcnt_res, part, pg, pc);
  k6_final<<<N_GRAPHS, 256, 0, stream>>>(part, pg, pc, pooled_res, gcnt_res,
                                         z, lin1_w, lin1_b, lin2_w, lin2_b, out);
}